// Round 2
// baseline (186.822 us; speedup 1.0000x reference)
//
#include <hip/hip_runtime.h>
#include <hip/hip_bf16.h>

// Problem: MultiHeadGraphAttentionLayer_28956669509709  (fp32 I/O per reference)
// Identity: sum_j softmax(e)[...,j] == 1  =>  attention is a no-op, out = hp.
// out[b,n,h*64+d] = a*hp[h,b,n,d] + (1-a)*h[b,n,h*64+d],  a = clip(res_alpha,0,1)
// => one GEMM [16384x256] @ Wc[256x256] (bf16 MFMA, fp32 acc) + residual blend.
// adj (134 MB fp32) is never touched.

typedef unsigned short ushort_t;
typedef __bf16 bf16x8 __attribute__((ext_vector_type(8)));
typedef float floatx4 __attribute__((ext_vector_type(4)));

__device__ __forceinline__ float bf2f(ushort_t u) {
    unsigned int x = ((unsigned int)u) << 16;
    float f;
    __builtin_memcpy(&f, &x, 4);
    return f;
}

__device__ __forceinline__ ushort_t f2bf(float f) {
    unsigned int x;
    __builtin_memcpy(&x, &f, 4);
    // round to nearest even
    return (ushort_t)((x + 0x7fffu + ((x >> 16) & 1u)) >> 16);
}

// ---------------------------------------------------------------------------
// Kernel 1: W fp32 [H=4][F=256][D=64] -> Wt bf16 [n=h*64+d][k=f]  (256x256)
// grid: 16 blocks (h = bid>>2, f-chunk = bid&3), 256 threads
// ---------------------------------------------------------------------------
__global__ __launch_bounds__(256) void transpose_w(const float* __restrict__ W,
                                                   ushort_t* __restrict__ Wt) {
    __shared__ ushort_t tile[64][72];  // [f_local][d], +8 pad breaks bank stride
    const int h  = blockIdx.x >> 2;
    const int f0 = (blockIdx.x & 3) * 64;
    const int t  = threadIdx.x;

    // coalesced fp32 load (d contiguous per f-row), convert to bf16 into LDS
    #pragma unroll
    for (int p = 0; p < 2; ++p) {
        const int fl = p * 32 + (t >> 3);
        const int d0 = (t & 7) * 8;
        const float* src = W + h * 16384 + (f0 + fl) * 64 + d0;
        float4 v0 = *(const float4*)(src);
        float4 v1 = *(const float4*)(src + 4);
        ushort_t tmp[8] = { f2bf(v0.x), f2bf(v0.y), f2bf(v0.z), f2bf(v0.w),
                            f2bf(v1.x), f2bf(v1.y), f2bf(v1.z), f2bf(v1.w) };
        *(uint4*)&tile[fl][d0] = *(const uint4*)tmp;
    }
    __syncthreads();

    // transposed write: row n = h*64 + d, cols f0..f0+63 (k-contiguous)
    #pragma unroll
    for (int p = 0; p < 2; ++p) {
        const int dl  = p * 32 + (t >> 3);
        const int fl0 = (t & 7) * 8;
        ushort_t tmp[8];
        #pragma unroll
        for (int j = 0; j < 8; ++j) tmp[j] = tile[fl0 + j][dl];
        *(uint4*)(Wt + (size_t)(h * 64 + dl) * 256 + f0 + fl0) = *(const uint4*)tmp;
    }
}

// ---------------------------------------------------------------------------
// Kernel 2: out = a * (h @ Wc) + (1-a) * h   (fp32 in/out, bf16 MFMA inside)
//   grid: 256 blocks x 256 threads; block tile = 64 rows x 256 cols
//   wave w: 64 rows x cols [w*64, w*64+64) -> 4x4 tiles of 16x16x32 MFMA
// ---------------------------------------------------------------------------
#define LDS_STRIDE 264  // 256 + 8 pad

__global__ __launch_bounds__(256) void gat_gemm(const float* __restrict__ hIn,
                                                const ushort_t* __restrict__ Wt,
                                                const float* __restrict__ alpha_p,
                                                float* __restrict__ out) {
    __shared__ ushort_t hA[64 * LDS_STRIDE];
    const int t  = threadIdx.x;
    const int m0 = blockIdx.x * 64;

    // stage 64x256 fp32 h-tile -> bf16 LDS, coalesced float4 loads
    #pragma unroll
    for (int i = 0; i < 8; ++i) {
        const int c   = i * 256 + t;      // 2048 chunks of 8 elements
        const int row = c >> 5;
        const int k8  = (c & 31) * 8;
        const float* src = hIn + (size_t)(m0 + row) * 256 + k8;
        float4 v0 = *(const float4*)(src);
        float4 v1 = *(const float4*)(src + 4);
        ushort_t tmp[8] = { f2bf(v0.x), f2bf(v0.y), f2bf(v0.z), f2bf(v0.w),
                            f2bf(v1.x), f2bf(v1.y), f2bf(v1.z), f2bf(v1.w) };
        *(uint4*)(hA + row * LDS_STRIDE + k8) = *(const uint4*)tmp;
    }
    __syncthreads();

    const int w    = t >> 6;
    const int lane = t & 63;
    const int quad = lane >> 4;
    const int l16  = lane & 15;
    const int n0   = w * 64;

    floatx4 acc[4][4] = {};

    #pragma unroll
    for (int kt = 0; kt < 8; ++kt) {
        const int k0 = kt * 32 + quad * 8;
        bf16x8 a[4], b[4];
        #pragma unroll
        for (int mt = 0; mt < 4; ++mt)
            a[mt] = *(const bf16x8*)(hA + (mt * 16 + l16) * LDS_STRIDE + k0);
        #pragma unroll
        for (int nt = 0; nt < 4; ++nt)
            b[nt] = *(const bf16x8*)(Wt + (size_t)(n0 + nt * 16 + l16) * 256 + k0);
        #pragma unroll
        for (int mt = 0; mt < 4; ++mt)
            #pragma unroll
            for (int nt = 0; nt < 4; ++nt)
                acc[mt][nt] = __builtin_amdgcn_mfma_f32_16x16x32_bf16(
                    a[mt], b[nt], acc[mt][nt], 0, 0, 0);
    }

    // residual blend epilogue (fp32 out)
    float av = *alpha_p;
    av = fminf(fmaxf(av, 0.0f), 1.0f);
    const float bv = 1.0f - av;

    // C/D layout (m89-verified): col = lane&15, row = quad*4 + reg
    #pragma unroll
    for (int mt = 0; mt < 4; ++mt) {
        #pragma unroll
        for (int r = 0; r < 4; ++r) {
            const int rl = mt * 16 + quad * 4 + r;
            #pragma unroll
            for (int nt = 0; nt < 4; ++nt) {
                const int col = n0 + nt * 16 + l16;
                const float res = bf2f(hA[rl * LDS_STRIDE + col]);
                out[(size_t)(m0 + rl) * 256 + col] = av * acc[mt][nt][r] + bv * res;
            }
        }
    }
}

extern "C" void kernel_launch(void* const* d_in, const int* in_sizes, int n_in,
                              void* d_out, int out_size, void* d_ws, size_t ws_size,
                              hipStream_t stream) {
    // inputs (setup_inputs order, all fp32 per reference):
    //   d_in[0] h [8,2048,256], d_in[1] adj [8,2048,2048] (UNUSED),
    //   d_in[2] W [4,256,64],   d_in[3] res_alpha scalar
    const float* h_ptr = (const float*)d_in[0];
    const float* W_ptr = (const float*)d_in[2];
    const float* a_ptr = (const float*)d_in[3];
    float* out_ptr     = (float*)d_out;
    ushort_t* Wt       = (ushort_t*)d_ws;  // 256*256*2 = 128 KB scratch

    transpose_w<<<16, 256, 0, stream>>>(W_ptr, Wt);
    gat_gemm<<<256, 256, 0, stream>>>(h_ptr, Wt, a_ptr, out_ptr);
}